// Round 8
// baseline (66.967 us; speedup 1.0000x reference)
//
#include <hip/hip_runtime.h>
#include <math.h>

#define W_POS 0.1f
#define W_SCALE 0.1f
#define W_ROT 0.1f
#define W_COLOR 0.1f

#define RPT 4            // rows per wave
#define NWAVES 2048      // 8192 / RPT
#define NBLOCKS 512      // NWAVES / 4

struct F3 { float x, y, z; };

__device__ __forceinline__ unsigned umed3(unsigned a, unsigned b, unsigned c) {
    unsigned d;
    asm("v_med3_u32 %0, %1, %2, %3" : "=v"(d) : "v"(a), "v"(b), "v"(c));
    return d;
}
__device__ __forceinline__ unsigned umin_(unsigned a, unsigned b) {
    unsigned d;
    asm("v_min_u32 %0, %1, %2" : "=v"(d) : "v"(a), "v"(b));
    return d;
}

// Insert into ascending sorted 7-list E[0..6] (drops current max).
// E[k] = min(E[k], max(E[k-1], key)) == med3(key, E[k-1], E[k]) since sorted.
// Top-down order: every update reads OLD neighbor -> 7 independent ops.
#define INSERT7A(E, keyv) do { unsigned _k = (keyv);   \
    E[6] = umed3(_k, E[5], E[6]);                      \
    E[5] = umed3(_k, E[4], E[5]);                      \
    E[4] = umed3(_k, E[3], E[4]);                      \
    E[3] = umed3(_k, E[2], E[3]);                      \
    E[2] = umed3(_k, E[1], E[2]);                      \
    E[1] = umed3(_k, E[0], E[1]);                      \
    E[0] = umin_(E[0], _k);  } while (0)

// 7-round cross-lane merge of 64 sorted lists: OUT[t] = t-th smallest overall.
// Keys unique (index in low bits) -> exactly one owner lane pops per round.
#define WAVE_MERGE7(E, OUT) do {                                     \
    _Pragma("unroll")                                                \
    for (int _t = 0; _t < 7; ++_t) {                                 \
        unsigned _v = E[0];                                          \
        _Pragma("unroll")                                            \
        for (int _o = 32; _o; _o >>= 1)                              \
            _v = umin_(_v, (unsigned)__shfl_xor((int)_v, _o, 64));   \
        OUT[_t] = _v;                                                \
        bool _own = (E[0] == _v);                                    \
        _Pragma("unroll")                                            \
        for (int _m = 0; _m < 6; ++_m) E[_m] = _own ? E[_m+1] : E[_m]; \
        E[6] = _own ? 0xFFFFFFFFu : E[6];                            \
    } } while (0)

// One wave owns rows {4*wid .. 4*wid+3}; lanes split the 8192 candidates.
// All waves issue identical candidate addresses -> shared L1/L2 stream.
// Last-finished block (fence+counter) sums all wave partials -> out.
__global__ __launch_bounds__(256, 2) void main_kernel(
    const float* __restrict__ pos,
    const float* __restrict__ scales,
    const float* __restrict__ rots,
    const float* __restrict__ colors,
    double* __restrict__ partials,
    unsigned* __restrict__ ctr,
    float* __restrict__ out, int n)
{
    const int lane = threadIdx.x & 63;
    const int wid = blockIdx.x * 4 + (threadIdx.x >> 6);
    const int rbase = wid * RPT;
    const F3* __restrict__ pos3 = (const F3*)pos;

    float rx[RPT], ry[RPT], rz[RPT];
#pragma unroll
    for (int k = 0; k < RPT; ++k) {
        F3 q = pos3[rbase + k];
        rx[k] = q.x; ry[k] = q.y; rz[k] = q.z;
    }

    unsigned e[RPT][7];
#pragma unroll
    for (int k = 0; k < RPT; ++k)
#pragma unroll
        for (int t = 0; t < 7; ++t) e[k][t] = 0xFFFFFFFFu;

    // hot loop: candidate j = t*64 + lane (identical across all waves)
#pragma unroll 4
    for (int t = 0; t < 128; ++t) {
        const int j = t * 64 + lane;
        F3 p = pos3[j];
        const unsigned ju = (unsigned)j;
#pragma unroll
        for (int k = 0; k < RPT; ++k) {
            // subtract form: exact 0 for self (-> smallest key), always >= 0
            float dx = rx[k] - p.x, dy = ry[k] - p.y, dz = rz[k] - p.z;
            float d2 = fmaf(dz, dz, fmaf(dy, dy, dx * dx));
            // truncate low 13 mantissa bits, pack index: orders like top_k
            // (distance asc, then smaller index)   -> v_and_or_b32
            unsigned key = (__float_as_uint(d2) & 0xFFFFE000u) | ju;
            INSERT7A(e[k], key);
        }
    }

    unsigned o[RPT][7];
#pragma unroll
    for (int k = 0; k < RPT; ++k) WAVE_MERGE7(e[k], o[k]);

    // ---- epilogue: 16 lanes per row ----
    const int q = lane >> 4;         // row sub-index 0..3
    const int l = lane & 15;
    const int r = rbase + q;
    const unsigned M = 0x1FFFu;
    const unsigned rr = (unsigned)r;

    // o[][] is wave-uniform; select row q statically (no dynamic reg indexing)
    unsigned oq[7];
#pragma unroll
    for (int t = 0; t < 7; ++t) {
        unsigned a = (q & 1) ? o[1][t] : o[0][t];
        unsigned b = (q & 1) ? o[3][t] : o[2][t];
        oq[t] = (q & 2) ? b : a;
    }

    // self-exclusion (self has exact d2=0 -> oq[0] in practice; stay general)
    int spos = ((oq[0] & M) == rr) ? 0 :
               ((oq[1] & M) == rr) ? 1 :
               ((oq[2] & M) == rr) ? 2 :
               ((oq[3] & M) == rr) ? 3 :
               ((oq[4] & M) == rr) ? 4 :
               ((oq[5] & M) == rr) ? 5 :
               ((oq[6] & M) == rr) ? 6 : 7;
    unsigned u0 = (spos == 0) ? oq[1] : oq[0];
    unsigned u1 = (spos <= 1) ? oq[2] : oq[1];
    unsigned u2 = (spos <= 2) ? oq[3] : oq[2];
    unsigned u3 = (spos <= 3) ? oq[4] : oq[3];
    unsigned u4 = (spos <= 4) ? oq[5] : oq[4];

    const float invn = 1.0f / (float)n;
    float contrib = 0.0f;
    if (l < 15) {
        // 5 nearest off-diag neighbors x 3 channels
        int t5 = l / 3, ch = l - 3 * t5;
        unsigned uk = u0;
        if (t5 == 1) uk = u1;
        if (t5 == 2) uk = u2;
        if (t5 == 3) uk = u3;
        if (t5 == 4) uk = u4;
        int nidx = (int)(uk & M);
        contrib = fabsf(colors[3*r+ch] - colors[3*nidx+ch]) * (W_COLOR * invn / 15.0f);
    } else {
        // lane 15 of each 16-group: pos loss (exact reference formula) +
        // scale + rotation + color-center
        int i2 = (int)(u1 & M);
        float qx = pos[3*r], qy = pos[3*r+1], qz = pos[3*r+2];
        float px = pos[3*i2], py = pos[3*i2+1], pz = pos[3*i2+2];
        float sq = qx*qx + qy*qy + qz*qz;
        float sp = px*px + py*py + pz*pz;
        float dot = fmaf(qx, px, fmaf(qy, py, qz * pz));
        float d2e = fmaxf(sq + sp - 2.0f * dot, 0.0f);
        contrib = expf(-sqrtf(d2e)) * (W_POS * invn);

        float s0 = scales[3*r], s1 = scales[3*r+1], s2 = scales[3*r+2];
        float m = (s0 + s1 + s2) * (1.0f / 3.0f);
        float var = ((s0-m)*(s0-m) + (s1-m)*(s1-m) + (s2-m)*(s2-m)) * 0.5f;
        float al = fabsf(s0 - 1.0f) + fabsf(s1 - 1.0f) + fabsf(s2 - 1.0f);
        contrib += W_SCALE * (al * (invn / 3.0f) + var * invn);

        float r0 = rots[4*r], r1 = rots[4*r+1], r2 = rots[4*r+2], r3 = rots[4*r+3];
        float nm = sqrtf(r0*r0 + r1*r1 + r2*r2 + r3*r3);
        contrib += W_ROT * (nm - 1.0f) * (nm - 1.0f) * invn;

        float c0 = colors[3*r], c1 = colors[3*r+1], c2 = colors[3*r+2];
        contrib += W_COLOR * ((c0-.5f)*(c0-.5f) + (c1-.5f)*(c1-.5f) + (c2-.5f)*(c2-.5f)) * (invn / 3.0f);
    }

    // wave sum (fixed butterfly, f64) -> one partial per wave
    double cd = (double)contrib;
#pragma unroll
    for (int off = 32; off; off >>= 1)
        cd += __shfl_xor(cd, off, 64);
    if (lane == 0) {
        partials[wid] = cd;
        __threadfence();                 // release this wave's partial
    }
    __syncthreads();

    __shared__ int lastflag;
    if (threadIdx.x == 0)
        lastflag = (atomicAdd(ctr, 1u) == NBLOCKS - 1) ? 1 : 0;
    __syncthreads();
    if (!lastflag) return;

    // last block: deterministic fixed-order sum of all 2048 wave partials
    __threadfence();                     // acquire
    double s = 0.0;
#pragma unroll
    for (int k = 0; k < NWAVES / 256; ++k)
        s += partials[k * 256 + threadIdx.x];

    __shared__ double sm[256];
    sm[threadIdx.x] = s;
    __syncthreads();
    for (int step = 128; step; step >>= 1) {
        if ((int)threadIdx.x < step) sm[threadIdx.x] += sm[threadIdx.x + step];
        __syncthreads();
    }
    if (threadIdx.x == 0) out[0] = (float)sm[0];
}

extern "C" void kernel_launch(void* const* d_in, const int* in_sizes, int n_in,
                              void* d_out, int out_size, void* d_ws, size_t ws_size,
                              hipStream_t stream) {
    const float* pos = (const float*)d_in[0];
    const float* scales = (const float*)d_in[1];
    const float* rots = (const float*)d_in[2];
    const float* colors = (const float*)d_in[3];
    int n = in_sizes[0] / 3;   // 8192

    double* partials = (double*)d_ws;                       // 2048 * 8 B
    unsigned* ctr = (unsigned*)((char*)d_ws + NWAVES * 8);

    hipMemsetAsync(ctr, 0, sizeof(unsigned), stream);
    main_kernel<<<NBLOCKS, 256, 0, stream>>>(pos, scales, rots, colors,
                                             partials, ctr, (float*)d_out, n);
}